// Round 13
// baseline (98.933 us; speedup 1.0000x reference)
//
#include <hip/hip_runtime.h>
#include <stdint.h>

// CorrelationLayer via MFMA Gram tiles — 8 output rows/block, spill-free.
// out[j*7+i, h, w] = sum_c x[c,h,w] * y[c,h+j-3,w+i-3], zero-padded.
//
// R13 = R12 (halo-amortized: 8 output rows/block, y staged 14 rows ->
// redundancy 1.75x) with the R12 spill removed:
//  - amdgpu_waves_per_eu(4,4): pin 4 waves/SIMD (the mandatory floor for a
//    16-wave block) -> 128-VGPR budget; stops the compiler squeezing to the
//    64-tier (R12: VGPR=64, WRITE 71MB = ~34MB scratch).
//  - staging unit = (row, kb, col-quad): 8x float4 loads (32 regs in flight),
//    560 units, tid<560 stage exactly one -> per-thread live state
//    acc(56)+af(16)+F(32)+addr ~= 119 < 128.
// All math byte-identical to passing R12: LDS [14 rows][40 cols][k32 pad40]
// bf16 k-contiguous (80 B/col); A/B frag lane {m|n}=l&15, k=(l>>4)*8+e;
// C/D col=lane&15, row=(lane>>4)*4+reg; extraction slab 16x34 f32, i=g/g+4.
// Block 1024 thr / 16 waves = (dh 0..7) x (ww 0..1); per chunk: issue kc+1
// loads -> compute kc (7j x 2 tiles, B row = dh+j) -> barrier -> write ->
// barrier. Grid 48 hg x 16 slabs = 768; XCD k owns hg [6k,6k+6).

typedef __attribute__((ext_vector_type(8))) short short8;
typedef __attribute__((ext_vector_type(4))) float floatx4;

constexpr int C = 128;
constexpr int H = 384;
constexpr int W = 512;
constexpr int HW = H * W;

constexpr int NROW = 14;              // rows h0-3 .. h0+10
constexpr int NCOL = 40;              // LDS col 0 = abs ws_blk - 4
constexpr int KP   = 40;              // bf16 per col (32 k + 8 pad) = 80 B
constexpr int ROWB = NCOL * KP * 2;   // 3200 B per row
constexpr int BUFE = NROW * NCOL * KP;        // 22400 bf16 elems (44.8 KB)
constexpr int NUNIT = NROW * 4 * (NCOL / 4);  // 560 staging units

__device__ __forceinline__ uint32_t pkbf(float a, float b) {
  uint32_t ua = (__float_as_uint(a) + 0x8000u) >> 16;
  uint32_t ub = (__float_as_uint(b) + 0x8000u) & 0xffff0000u;
  return ua | ub;
}

union S8U { uint32_t u[4]; short8 s; };

// decode staging unit u -> source pointer, validity, LDS element offset
__device__ __forceinline__ void unit_decode(const float* __restrict__ y,
                                            int kc, int h0, int ws_blk, int u,
                                            const float*& src, bool& val,
                                            int& ldso) {
  const int c4  = u % 10;
  const int kb  = (u / 10) & 3;
  const int row = u / 40;                    // 0..13
  const int r_abs = h0 - 3 + row;
  const int cb    = ws_blk - 4 + 4 * c4;     // mult of 4 -> no quad straddle
  val = (r_abs >= 0) & (r_abs < H) & (cb >= 0) & (cb <= W - 4);
  const int r  = r_abs < 0 ? 0 : (r_abs >= H ? H - 1 : r_abs);
  const int cc = cb < 0 ? 0 : (cb > W - 4 ? W - 4 : cb);
  src  = y + (size_t)(kc * 32 + kb * 8) * HW + (size_t)r * W + cc;
  ldso = (row * NCOL + 4 * c4) * KP + kb * 8;
}

// pack 8 k-planes x 4 cols (f[e] = float4 over cols) and write 4 b128s
__device__ __forceinline__ void unit_write(uint16_t* __restrict__ buf,
                                           const float4 f[8], bool val,
                                           int ldso) {
  uint4 v[4];
  v[0].x = pkbf(f[0].x, f[1].x); v[0].y = pkbf(f[2].x, f[3].x);
  v[0].z = pkbf(f[4].x, f[5].x); v[0].w = pkbf(f[6].x, f[7].x);
  v[1].x = pkbf(f[0].y, f[1].y); v[1].y = pkbf(f[2].y, f[3].y);
  v[1].z = pkbf(f[4].y, f[5].y); v[1].w = pkbf(f[6].y, f[7].y);
  v[2].x = pkbf(f[0].z, f[1].z); v[2].y = pkbf(f[2].z, f[3].z);
  v[2].z = pkbf(f[4].z, f[5].z); v[2].w = pkbf(f[6].z, f[7].z);
  v[3].x = pkbf(f[0].w, f[1].w); v[3].y = pkbf(f[2].w, f[3].w);
  v[3].z = pkbf(f[4].w, f[5].w); v[3].w = pkbf(f[6].w, f[7].w);
  if (!val) {
#pragma unroll
    for (int q = 0; q < 4; ++q) v[q] = make_uint4(0, 0, 0, 0);
  }
#pragma unroll
  for (int q = 0; q < 4; ++q)
    *reinterpret_cast<uint4*>(&buf[ldso + q * KP]) = v[q];
}

__global__ __launch_bounds__(1024)
__attribute__((amdgpu_waves_per_eu(4, 4)))
void corr_mfma(const float* __restrict__ x, const float* __restrict__ y,
               float* __restrict__ out) {
  __shared__ uint16_t ys[BUFE];              // 44800 B

  const int bid  = blockIdx.x;
  const int xcd  = bid & 7;
  const int idx  = bid >> 3;                 // 0..95
  const int hg   = xcd * 6 + (idx >> 4);     // 0..47
  const int slab = idx & 15;
  const int h0     = hg * 8;
  const int ws_blk = slab * 32;
  const int tid  = threadIdx.x;
  const int wv   = tid >> 6;                 // 0..15
  const int lane = tid & 63;
  const int m  = lane & 15;
  const int g  = lane >> 4;
  const int dh = wv >> 1;                    // 0..7
  const int ww = wv & 1;                     // 0..1
  const int h  = h0 + dh;
  const int ws = ws_blk + ww * 16;

  const bool stg = (tid < NUNIT);            // 560 staging threads

  floatx4 acc[7][2];
#pragma unroll
  for (int j = 0; j < 7; ++j) {
    acc[j][0] = (floatx4){0.f, 0.f, 0.f, 0.f};
    acc[j][1] = (floatx4){0.f, 0.f, 0.f, 0.f};
  }

  // ---- A fragments preload: af[kc], A[m][k] = x[k][h][ws+m], k=g*8+e ----
  short8 af[4];
  {
    const float* xb = x + (size_t)(g * 8) * HW + (size_t)h * W + (ws + m);
#pragma unroll
    for (int kc = 0; kc < 4; ++kc) {
      float f[8];
#pragma unroll
      for (int e = 0; e < 8; ++e) f[e] = xb[(size_t)(kc * 32 + e) * HW];
      S8U s;
      s.u[0] = pkbf(f[0], f[1]);
      s.u[1] = pkbf(f[2], f[3]);
      s.u[2] = pkbf(f[4], f[5]);
      s.u[3] = pkbf(f[6], f[7]);
      af[kc] = s.s;
    }
  }

  // per-lane b128 read byte-offsets within a row slab
  const int col0 = ww * 16 + m + 1;          // abs ws-3+m
  int col1 = col0 + 16;                      // tile1; clamp unused lanes
  if (col1 > NCOL - 1) col1 = NCOL - 1;
  const int fb0 = col0 * (KP * 2) + g * 16;
  const int fb1 = col1 * (KP * 2) + g * 16;

  // ---- prologue: stage chunk 0 ----
  if (stg) {
    const float* s0; bool v0; int o0;
    float4 F[8];
    unit_decode(y, 0, h0, ws_blk, tid, s0, v0, o0);
#pragma unroll
    for (int e = 0; e < 8; ++e)
      F[e] = *reinterpret_cast<const float4*>(s0 + (size_t)e * HW);
    unit_write(ys, F, v0, o0);
  }
  __syncthreads();

  // ---- main loop: issue-early loads, compute, barrier, write-late ----
#pragma unroll
  for (int kc = 0; kc < 4; ++kc) {
    const float* s0; bool v0 = false; int o0 = 0;
    float4 F[8];
    if (kc < 3 && stg) {                     // issue chunk kc+1's loads
      unit_decode(y, kc + 1, h0, ws_blk, tid, s0, v0, o0);
#pragma unroll
      for (int e = 0; e < 8; ++e)
        F[e] = *reinterpret_cast<const float4*>(s0 + (size_t)e * HW);
    }

    // compute chunk kc: B row = dh + j
#pragma unroll
    for (int j = 0; j < 7; ++j) {
      const uint8_t* rb =
          reinterpret_cast<const uint8_t*>(ys) + (dh + j) * ROWB;
      const short8 b0 = *reinterpret_cast<const short8*>(rb + fb0);
      const short8 b1 = *reinterpret_cast<const short8*>(rb + fb1);
      acc[j][0] = __builtin_amdgcn_mfma_f32_16x16x32_bf16(af[kc], b0, acc[j][0], 0, 0, 0);
      acc[j][1] = __builtin_amdgcn_mfma_f32_16x16x32_bf16(af[kc], b1, acc[j][1], 0, 0, 0);
    }
    __syncthreads();                         // all reads of ys done

    if (kc < 3) {
      if (stg) unit_write(ys, F, v0, o0);
      __syncthreads();                       // writes visible before compute
    }
  }

  // ---- extraction: per-wave 16x34 f32 slab (reuses ys; 16*2176B fits) ----
  float* slabp = reinterpret_cast<float*>(ys) + wv * 544;
#pragma unroll
  for (int j = 0; j < 7; ++j) {
#pragma unroll
    for (int q = 0; q < 4; ++q) {
      slabp[(g * 4 + q) * 34 + m]      = acc[j][0][q];   // cols 0..15
      slabp[(g * 4 + q) * 34 + 16 + m] = acc[j][1][q];   // cols 16..31
    }
    const float vo0 = slabp[m * 34 + m + g];             // i = g
    const float vo1 = slabp[m * 34 + m + g + 4];         // i = g+4 (g<3)
    float* ob = out + (size_t)(j * 7 + g) * HW + (size_t)h * W + (ws + m);
    *ob = vo0;
    if (g < 3) ob[(size_t)4 * HW] = vo1;
  }
}

extern "C" void kernel_launch(void* const* d_in, const int* in_sizes, int n_in,
                              void* d_out, int out_size, void* d_ws, size_t ws_size,
                              hipStream_t stream) {
  const float* x = (const float*)d_in[0];
  const float* y = (const float*)d_in[1];
  float* out = (float*)d_out;
  corr_mfma<<<dim3(48 * 16), dim3(1024), 0, stream>>>(x, y, out);
}

// Round 14
// 66.923 us; speedup vs baseline: 1.4783x; 1.4783x over previous
//
#include <hip/hip_runtime.h>
#include <stdint.h>

// CorrelationLayer via MFMA Gram tiles — 8 output rows/block, no reg pipeline.
// out[j*7+i, h, w] = sum_c x[c,h,w] * y[c,h+j-3,w+i-3], zero-padded.
//
// R14 = R12 structure (halo-amortized: block = 8 output rows x 32-px slab,
// y staged 14 rows -> 280 staged-elems per output px vs R7's 1008) MINUS the
// issue-early/write-late register pipeline. Session lesson (R8/R10/R12/R13):
// >=512-thr blocks get a 64-VGPR allocation and SPILL any registers held
// across the compute phase (R12 WRITE 71MB, R13 102MB vs 37.6MB output).
// Staging is now load->pack->ds_write inline within the staging phase, so
// no float4[8] lives across the 14-MFMA compute. acc -> AGPRs, af 16 VGPR.
// Latency cover: 2-3 resident blocks/CU interleave; y band (14 rows x 128ch
// = 3.7MB) is L2-resident per XCD thanks to slab-fastest grid order.
// All math byte-identical to passing R12/R13: LDS [14 rows][40 cols][k32
// pad40] bf16 k-contiguous (80 B/col); A/B frag lane {m|n}=l&15,
// k=(l>>4)*8+e; C/D col=lane&15, row=(lane>>4)*4+reg; extraction slab 16x34
// f32, i=g/g+4 (g<3). Grid 48 hg x 16 slabs = 768; XCD k owns hg [6k,6k+6).

typedef __attribute__((ext_vector_type(8))) short short8;
typedef __attribute__((ext_vector_type(4))) float floatx4;

constexpr int C = 128;
constexpr int H = 384;
constexpr int W = 512;
constexpr int HW = H * W;

constexpr int NROW = 14;              // rows h0-3 .. h0+10
constexpr int NCOL = 40;              // LDS col 0 = abs ws_blk - 4
constexpr int KP   = 40;              // bf16 per col (32 k + 8 pad) = 80 B
constexpr int ROWB = NCOL * KP * 2;   // 3200 B per row
constexpr int BUFE = NROW * NCOL * KP;        // 22400 bf16 elems (44.8 KB)
constexpr int NUNIT = NROW * 4 * (NCOL / 4);  // 560 staging units

__device__ __forceinline__ uint32_t pkbf(float a, float b) {
  uint32_t ua = (__float_as_uint(a) + 0x8000u) >> 16;
  uint32_t ub = (__float_as_uint(b) + 0x8000u) & 0xffff0000u;
  return ua | ub;
}

union S8U { uint32_t u[4]; short8 s; };

// stage one unit: (row, kb, col-quad) = 8 k-planes x 4 cols, inline pack+write
__device__ __forceinline__ void stage_unit(const float* __restrict__ y,
                                           uint16_t* __restrict__ buf,
                                           int kc, int h0, int ws_blk, int u) {
  const int c4  = u % 10;
  const int kb  = (u / 10) & 3;
  const int row = u / 40;                    // 0..13
  const int r_abs = h0 - 3 + row;
  const int cb    = ws_blk - 4 + 4 * c4;     // mult of 4 -> no quad straddle
  const bool val = (r_abs >= 0) & (r_abs < H) & (cb >= 0) & (cb <= W - 4);
  const int r  = r_abs < 0 ? 0 : (r_abs >= H ? H - 1 : r_abs);
  const int cc = cb < 0 ? 0 : (cb > W - 4 ? W - 4 : cb);
  const float* src = y + (size_t)(kc * 32 + kb * 8) * HW + (size_t)r * W + cc;
  float4 f[8];
#pragma unroll
  for (int e = 0; e < 8; ++e)
    f[e] = *reinterpret_cast<const float4*>(src + (size_t)e * HW);
  const int ldso = (row * NCOL + 4 * c4) * KP + kb * 8;
  uint4 v[4];
  v[0].x = pkbf(f[0].x, f[1].x); v[0].y = pkbf(f[2].x, f[3].x);
  v[0].z = pkbf(f[4].x, f[5].x); v[0].w = pkbf(f[6].x, f[7].x);
  v[1].x = pkbf(f[0].y, f[1].y); v[1].y = pkbf(f[2].y, f[3].y);
  v[1].z = pkbf(f[4].y, f[5].y); v[1].w = pkbf(f[6].y, f[7].y);
  v[2].x = pkbf(f[0].z, f[1].z); v[2].y = pkbf(f[2].z, f[3].z);
  v[2].z = pkbf(f[4].z, f[5].z); v[2].w = pkbf(f[6].z, f[7].z);
  v[3].x = pkbf(f[0].w, f[1].w); v[3].y = pkbf(f[2].w, f[3].w);
  v[3].z = pkbf(f[4].w, f[5].w); v[3].w = pkbf(f[6].w, f[7].w);
  if (!val) {
#pragma unroll
    for (int q = 0; q < 4; ++q) v[q] = make_uint4(0, 0, 0, 0);
  }
#pragma unroll
  for (int q = 0; q < 4; ++q)
    *reinterpret_cast<uint4*>(&buf[ldso + q * KP]) = v[q];
}

__global__ __launch_bounds__(1024, 2)
void corr_mfma(const float* __restrict__ x, const float* __restrict__ y,
               float* __restrict__ out) {
  __shared__ uint16_t ys[BUFE];              // 44800 B

  const int bid  = blockIdx.x;
  const int xcd  = bid & 7;
  const int idx  = bid >> 3;                 // 0..95
  const int hg   = xcd * 6 + (idx >> 4);     // 0..47
  const int slab = idx & 15;
  const int h0     = hg * 8;
  const int ws_blk = slab * 32;
  const int tid  = threadIdx.x;
  const int wv   = tid >> 6;                 // 0..15
  const int lane = tid & 63;
  const int m  = lane & 15;
  const int g  = lane >> 4;
  const int dh = wv >> 1;                    // 0..7
  const int ww = wv & 1;                     // 0..1
  const int h  = h0 + dh;
  const int ws = ws_blk + ww * 16;

  const bool stg = (tid < NUNIT);            // 560 staging threads

  floatx4 acc[7][2];
#pragma unroll
  for (int j = 0; j < 7; ++j) {
    acc[j][0] = (floatx4){0.f, 0.f, 0.f, 0.f};
    acc[j][1] = (floatx4){0.f, 0.f, 0.f, 0.f};
  }

  // ---- A fragments preload: af[kc], A[m][k] = x[k][h][ws+m], k=g*8+e ----
  short8 af[4];
  {
    const float* xb = x + (size_t)(g * 8) * HW + (size_t)h * W + (ws + m);
#pragma unroll
    for (int kc = 0; kc < 4; ++kc) {
      float f[8];
#pragma unroll
      for (int e = 0; e < 8; ++e) f[e] = xb[(size_t)(kc * 32 + e) * HW];
      S8U s;
      s.u[0] = pkbf(f[0], f[1]);
      s.u[1] = pkbf(f[2], f[3]);
      s.u[2] = pkbf(f[4], f[5]);
      s.u[3] = pkbf(f[6], f[7]);
      af[kc] = s.s;
    }
  }

  // per-lane b128 read byte-offsets within a row slab
  const int col0 = ww * 16 + m + 1;          // abs ws-3+m
  int col1 = col0 + 16;                      // tile1; clamp unused lanes
  if (col1 > NCOL - 1) col1 = NCOL - 1;
  const int fb0 = col0 * (KP * 2) + g * 16;
  const int fb1 = col1 * (KP * 2) + g * 16;

  // ---- main loop: plain stage -> barrier -> compute -> barrier ----
#pragma unroll
  for (int kc = 0; kc < 4; ++kc) {
    if (kc) __syncthreads();                 // reads of previous chunk done
    if (stg) stage_unit(y, ys, kc, h0, ws_blk, tid);
    __syncthreads();

    // compute chunk kc: B row = dh + j
#pragma unroll
    for (int j = 0; j < 7; ++j) {
      const uint8_t* rb =
          reinterpret_cast<const uint8_t*>(ys) + (dh + j) * ROWB;
      const short8 b0 = *reinterpret_cast<const short8*>(rb + fb0);
      const short8 b1 = *reinterpret_cast<const short8*>(rb + fb1);
      acc[j][0] = __builtin_amdgcn_mfma_f32_16x16x32_bf16(af[kc], b0, acc[j][0], 0, 0, 0);
      acc[j][1] = __builtin_amdgcn_mfma_f32_16x16x32_bf16(af[kc], b1, acc[j][1], 0, 0, 0);
    }
  }

  // ---- extraction: per-wave 16x34 f32 slab (reuses ys; 16*2176B fits) ----
  __syncthreads();
  float* slabp = reinterpret_cast<float*>(ys) + wv * 544;
#pragma unroll
  for (int j = 0; j < 7; ++j) {
#pragma unroll
    for (int q = 0; q < 4; ++q) {
      slabp[(g * 4 + q) * 34 + m]      = acc[j][0][q];   // cols 0..15
      slabp[(g * 4 + q) * 34 + 16 + m] = acc[j][1][q];   // cols 16..31
    }
    const float vo0 = slabp[m * 34 + m + g];             // i = g
    const float vo1 = slabp[m * 34 + m + g + 4];         // i = g+4 (g<3)
    float* ob = out + (size_t)(j * 7 + g) * HW + (size_t)h * W + (ws + m);
    *ob = vo0;
    if (g < 3) ob[(size_t)4 * HW] = vo1;
  }
}

extern "C" void kernel_launch(void* const* d_in, const int* in_sizes, int n_in,
                              void* d_out, int out_size, void* d_ws, size_t ws_size,
                              hipStream_t stream) {
  const float* x = (const float*)d_in[0];
  const float* y = (const float*)d_in[1];
  float* out = (float*)d_out;
  corr_mfma<<<dim3(48 * 16), dim3(1024), 0, stream>>>(x, y, out);
}

// Round 15
// 65.999 us; speedup vs baseline: 1.4990x; 1.0140x over previous
//
#include <hip/hip_runtime.h>
#include <stdint.h>

// CorrelationLayer via MFMA Gram tiles — 8 output rows/block, balanced
// col-pair staging + kb-XOR bank swizzle.
// out[j*7+i, h, w] = sum_c x[c,h,w] * y[c,h+j-3,w+i-3], zero-padded.
//
// R15 = R14 (best: 66.9us) with two fixes, math byte-identical:
//  1. staging unit = col-PAIR (1120 units ~1.09/thread): all 16 waves stage
//     (R14: 560 units -> waves 9..15 idle), float2[8]=16 temp regs -> no
//     spill in the 64-VGPR big-block budget (R14 WRITE 51MB vs 37.6 output).
//  2. kb-XOR swizzle: k-block stored at kb^((c2>>2)&3) (16B granules);
//     read inverts with g^((col>>3)&3). Write conflicts 5-way -> 2-way
//     (R14: 5.9M conflict-cycles ~ 14% of runtime); read stays 2-way.
// Structure (R12/R14 verified): block 1024 thr / 16 waves = 8 output rows x
// 32-px slab; wave (dh 0..7, ww 0..1) owns (h0+dh, 16-px tile), all 7 j.
// LDS [14 rows][40 cols][k32 pad40] bf16 k-contiguous (80 B/col), 44.8 KB.
// A/B frag lane {m|n}=l&15, k=(l>>4)*8+e; C/D col=lane&15,row=(lane>>4)*4+reg;
// extraction slab 16x34 f32, i=g / g+4 (g<3).
// Grid 48 hg x 16 slabs = 768; XCD k owns hg [6k,6k+6), slab-fastest.

typedef __attribute__((ext_vector_type(8))) short short8;
typedef __attribute__((ext_vector_type(4))) float floatx4;

constexpr int C = 128;
constexpr int H = 384;
constexpr int W = 512;
constexpr int HW = H * W;

constexpr int NROW = 14;              // rows h0-3 .. h0+10
constexpr int NCOL = 40;              // LDS col 0 = abs ws_blk - 4
constexpr int KP   = 40;              // bf16 per col (32 k + 8 pad) = 80 B
constexpr int ROWB = NCOL * KP * 2;   // 3200 B per row
constexpr int BUFE = NROW * NCOL * KP;        // 22400 bf16 elems (44.8 KB)
constexpr int NUNIT = NROW * 4 * (NCOL / 2);  // 1120 staging units

__device__ __forceinline__ uint32_t pkbf(float a, float b) {
  uint32_t ua = (__float_as_uint(a) + 0x8000u) >> 16;
  uint32_t ub = (__float_as_uint(b) + 0x8000u) & 0xffff0000u;
  return ua | ub;
}

union S8U { uint32_t u[4]; short8 s; };

// stage one unit: (row, kb, col-pair) = 8 k-planes x 2 cols; inline
// load -> pack -> swizzled ds_write (no regs live across compute phases).
__device__ __forceinline__ void stage_unit(const float* __restrict__ y,
                                           uint16_t* __restrict__ buf,
                                           int kc, int h0, int ws_blk, int u) {
  const int c2  = u % 20;
  const int kb  = (u / 20) & 3;
  const int row = u / 80;                    // 0..13
  const int r_abs = h0 - 3 + row;
  const int cb    = ws_blk - 4 + 2 * c2;     // even -> no pair straddle
  const bool val = (r_abs >= 0) & (r_abs < H) & (cb >= 0) & (cb <= W - 2);
  const int r  = r_abs < 0 ? 0 : (r_abs >= H ? H - 1 : r_abs);
  const int cc = cb < 0 ? 0 : (cb > W - 2 ? W - 2 : cb);
  const float* src = y + (size_t)(kc * 32 + kb * 8) * HW + (size_t)r * W + cc;
  float2 f[8];
#pragma unroll
  for (int e = 0; e < 8; ++e)
    f[e] = *reinterpret_cast<const float2*>(src + (size_t)e * HW);
  uint4 v0, v1;
  v0.x = pkbf(f[0].x, f[1].x); v0.y = pkbf(f[2].x, f[3].x);
  v0.z = pkbf(f[4].x, f[5].x); v0.w = pkbf(f[6].x, f[7].x);
  v1.x = pkbf(f[0].y, f[1].y); v1.y = pkbf(f[2].y, f[3].y);
  v1.z = pkbf(f[4].y, f[5].y); v1.w = pkbf(f[6].y, f[7].y);
  if (!val) { v0 = make_uint4(0, 0, 0, 0); v1 = make_uint4(0, 0, 0, 0); }
  const int kbs  = kb ^ ((c2 >> 2) & 3);     // bank swizzle (16B granule)
  const int ldso = (row * NCOL + 2 * c2) * KP + kbs * 8;
  *reinterpret_cast<uint4*>(&buf[ldso])      = v0;
  *reinterpret_cast<uint4*>(&buf[ldso + KP]) = v1;   // same quad -> same swz
}

__global__ __launch_bounds__(1024, 2)
void corr_mfma(const float* __restrict__ x, const float* __restrict__ y,
               float* __restrict__ out) {
  __shared__ uint16_t ys[BUFE];              // 44800 B

  const int bid  = blockIdx.x;
  const int xcd  = bid & 7;
  const int idx  = bid >> 3;                 // 0..95
  const int hg   = xcd * 6 + (idx >> 4);     // 0..47
  const int slab = idx & 15;
  const int h0     = hg * 8;
  const int ws_blk = slab * 32;
  const int tid  = threadIdx.x;
  const int wv   = tid >> 6;                 // 0..15
  const int lane = tid & 63;
  const int m  = lane & 15;
  const int g  = lane >> 4;
  const int dh = wv >> 1;                    // 0..7
  const int ww = wv & 1;                     // 0..1
  const int h  = h0 + dh;
  const int ws = ws_blk + ww * 16;

  const bool has2 = (tid < NUNIT - 1024);    // 96 threads own a 2nd unit

  floatx4 acc[7][2];
#pragma unroll
  for (int j = 0; j < 7; ++j) {
    acc[j][0] = (floatx4){0.f, 0.f, 0.f, 0.f};
    acc[j][1] = (floatx4){0.f, 0.f, 0.f, 0.f};
  }

  // ---- A fragments preload: af[kc], A[m][k] = x[k][h][ws+m], k=g*8+e ----
  short8 af[4];
  {
    const float* xb = x + (size_t)(g * 8) * HW + (size_t)h * W + (ws + m);
#pragma unroll
    for (int kc = 0; kc < 4; ++kc) {
      float f[8];
#pragma unroll
      for (int e = 0; e < 8; ++e) f[e] = xb[(size_t)(kc * 32 + e) * HW];
      S8U s;
      s.u[0] = pkbf(f[0], f[1]);
      s.u[1] = pkbf(f[2], f[3]);
      s.u[2] = pkbf(f[4], f[5]);
      s.u[3] = pkbf(f[6], f[7]);
      af[kc] = s.s;
    }
  }

  // per-lane b128 read byte-offsets within a row slab (swizzle-inverted)
  const int col0 = ww * 16 + m + 1;          // abs ws-3+m
  int col1 = col0 + 16;                      // tile1; clamp unused lanes
  if (col1 > NCOL - 1) col1 = NCOL - 1;
  const int fb0 = col0 * (KP * 2) + (g ^ ((col0 >> 3) & 3)) * 16;
  const int fb1 = col1 * (KP * 2) + (g ^ ((col1 >> 3) & 3)) * 16;

  // ---- main loop: plain stage -> barrier -> compute -> barrier ----
#pragma unroll
  for (int kc = 0; kc < 4; ++kc) {
    if (kc) __syncthreads();                 // reads of previous chunk done
    stage_unit(y, ys, kc, h0, ws_blk, tid);
    if (has2) stage_unit(y, ys, kc, h0, ws_blk, 1024 + tid);
    __syncthreads();

    // compute chunk kc: B row = dh + j
#pragma unroll
    for (int j = 0; j < 7; ++j) {
      const uint8_t* rb =
          reinterpret_cast<const uint8_t*>(ys) + (dh + j) * ROWB;
      const short8 b0 = *reinterpret_cast<const short8*>(rb + fb0);
      const short8 b1 = *reinterpret_cast<const short8*>(rb + fb1);
      acc[j][0] = __builtin_amdgcn_mfma_f32_16x16x32_bf16(af[kc], b0, acc[j][0], 0, 0, 0);
      acc[j][1] = __builtin_amdgcn_mfma_f32_16x16x32_bf16(af[kc], b1, acc[j][1], 0, 0, 0);
    }
  }

  // ---- extraction: per-wave 16x34 f32 slab (reuses ys; 16*2176B fits) ----
  __syncthreads();
  float* slabp = reinterpret_cast<float*>(ys) + wv * 544;
#pragma unroll
  for (int j = 0; j < 7; ++j) {
#pragma unroll
    for (int q = 0; q < 4; ++q) {
      slabp[(g * 4 + q) * 34 + m]      = acc[j][0][q];   // cols 0..15
      slabp[(g * 4 + q) * 34 + 16 + m] = acc[j][1][q];   // cols 16..31
    }
    const float vo0 = slabp[m * 34 + m + g];             // i = g
    const float vo1 = slabp[m * 34 + m + g + 4];         // i = g+4 (g<3)
    float* ob = out + (size_t)(j * 7 + g) * HW + (size_t)h * W + (ws + m);
    *ob = vo0;
    if (g < 3) ob[(size_t)4 * HW] = vo1;
  }
}

extern "C" void kernel_launch(void* const* d_in, const int* in_sizes, int n_in,
                              void* d_out, int out_size, void* d_ws, size_t ws_size,
                              hipStream_t stream) {
  const float* x = (const float*)d_in[0];
  const float* y = (const float*)d_in[1];
  float* out = (float*)d_out;
  corr_mfma<<<dim3(48 * 16), dim3(1024), 0, stream>>>(x, y, out);
}